// Round 9
// baseline (143.778 us; speedup 1.0000x reference)
//
#include <hip/hip_runtime.h>
#include <math.h>

// Problem constants (B,S,D,P,M from the reference)
#define BB 4
#define SS 8192
#define DD 512
#define PP 32
#define TT (PP + SS)            // 8224 tokens after concat
#define EPSV 1e-5f

typedef float f4 __attribute__((ext_vector_type(4)));

// Algebraic collapse (round 1): state0=0 => attn uniform => out[b,t,:] =
// (LN(cbar@Wv+bv)*g+b)@Wout+bout, cbar = mean_T concat(pm,x). Wk/bk/Wq/bq dead.
//
// Round 3 lesson: atomic-counter grid barrier ~77us (cross-XCD storm).
// Round 5 lesson: xN-redundant full matvec is latency-bound => split-K.
// Round 7 lesson: nontemporal hints neutral-to-negative => plain loads.
// Round 8 lessons: LN-affine decomposition (z = inv*Az - inv*mu*G + Bz)
// works; but colsum at 256 blocks (8 waves/CU) lost ~3.5us vs 1024 blocks
// => streaming reductions want full 32-waves/CU oversubscription.
//
// ws layout (floats):
//   part [1024*DD] colsum per-block partials (plain store)
//   pmsum[DD]      column-sum of persistent_memory (aux block)
//   Az   [BB*DD]   split-K accum of sum_d (v*gamma)[d]*Wout[d,:] (atomics)
//   G    [DD]      gamma@Wout                                    (atomics)
//   Bz   [DD]      beta@Wout + bout                              (atomics)
//   sv   [BB*16]   per-batch sum(v)   (stride 16 = separate cachelines)
//   sv2  [BB*16]   per-batch sum(v^2)

#define OFF_PART  0
#define OFF_PMSUM (1024 * DD)
#define OFF_AZ    (OFF_PMSUM + DD)
#define OFF_G     (OFF_AZ + BB * DD)
#define OFF_BZ    (OFF_G + DD)
#define OFF_SV    (OFF_BZ + DD)
#define OFF_SV2   (OFF_SV + BB * 16)

// ---------------------------------------------------------------------------
// Stage 1: blocks 0..1023: part[blk,:] = column-sum of a 32-row chunk of x
// (8 f4 loads/thread, 8192 waves = full oversubscription — round 4 config).
// Block 1024: pmsum. Block 1025: init stage-2 accumulators.
// ---------------------------------------------------------------------------
__global__ __launch_bounds__(512) void k_colsum(const f4* __restrict__ x4,
                                                const float* __restrict__ pm,
                                                const float* __restrict__ bout,
                                                float* __restrict__ ws) {
  const int tid = threadIdx.x;

  if (blockIdx.x < 1024) {
    const int bb    = blockIdx.x >> 8;    // batch (256 chunks per batch)
    const int chunk = blockIdx.x & 255;   // 32-row chunk
    const f4* p = x4 + ((size_t)bb * SS + (size_t)chunk * 32) * (DD / 4);

    f4 a = {0.f, 0.f, 0.f, 0.f};
#pragma unroll
    for (int i = 0; i < 8; ++i)           // 8*512 f4 = 32 rows
      a += p[i * 512 + tid];

    __shared__ f4 sh[512];
    sh[tid] = a;
    __syncthreads();
    if (tid < 128) {
      f4 r = sh[tid] + sh[tid + 128] + sh[tid + 256] + sh[tid + 384];
      ((f4*)(ws + OFF_PART))[blockIdx.x * 128 + tid] = r;
    }
  } else if (blockIdx.x == 1024) {
    float s = 0.f;
#pragma unroll
    for (int p = 0; p < PP; ++p) s += pm[p * DD + tid];
    ws[OFF_PMSUM + tid] = s;
  } else {
#pragma unroll
    for (int k = 0; k < BB; ++k) ws[OFF_AZ + k * DD + tid] = 0.f;
    ws[OFF_G + tid]  = 0.f;
    ws[OFF_BZ + tid] = bout[tid];
    if (tid < BB) { ws[OFF_SV + tid * 16] = 0.f; ws[OFF_SV2 + tid * 16] = 0.f; }
  }
}

// ---------------------------------------------------------------------------
// Stage 2 (single middle dispatch): 128 blocks = 4 batches x 32 column-slices.
//   A: cbar[j] = (sum of 256 part rows + pmsum)/T            -> LDS
//   B: v[c in slice] = sum_k cbar[k]*Wv[k, slice*16+c] + bv  (full K, 16 cols)
//   C: atomicAdd per-batch scalars sum(v), sum(v^2)
//   D: split-K row-chunks: Az += (v*gamma)[slice] @ Wout[slice,:]
//      batch-1 blocks also do G-chunks, batch-2 blocks Bz-chunks.
// ---------------------------------------------------------------------------
__global__ __launch_bounds__(512) void k_mid(const float* __restrict__ Wv,
                                             const float* __restrict__ bv,
                                             const float* __restrict__ gamma,
                                             const float* __restrict__ beta,
                                             const float* __restrict__ Wout,
                                             float* __restrict__ ws) {
  const int bb    = blockIdx.x >> 5;    // batch
  const int slice = blockIdx.x & 31;    // 16-column slice of v
  const int tid   = threadIdx.x;

  __shared__ float cbar[DD];
  __shared__ float red[8][16];
  __shared__ float vgSh[16];

  // Phase A: full cbar for this batch (256 partial rows + pmsum), 4-way ILP
  {
    const float* pb = ws + OFF_PART + (size_t)(bb * 256) * DD + tid;
    float s0 = 0.f, s1 = 0.f, s2 = 0.f, s3 = 0.f;
#pragma unroll 8
    for (int r = 0; r < 64; ++r) {
      s0 += pb[(size_t)(4 * r) * DD];
      s1 += pb[(size_t)(4 * r + 1) * DD];
      s2 += pb[(size_t)(4 * r + 2) * DD];
      s3 += pb[(size_t)(4 * r + 3) * DD];
    }
    cbar[tid] = (s0 + s1 + s2 + s3 + ws[OFF_PMSUM + tid]) * (1.0f / (float)TT);
  }
  __syncthreads();

  // Phase B: v for the 16 columns of this slice (full K=512)
  const int c = tid & 15;               // column within slice
  const int r = tid >> 4;               // 32 K-groups of 16
  {
    float acc = 0.f;
#pragma unroll
    for (int i = 0; i < 16; ++i) {
      const int k = r * 16 + i;
      acc += cbar[k] * Wv[k * DD + slice * 16 + c];
    }
    // reduce across r: in-wave (4 r-groups per wave), then across 8 waves
    acc += __shfl_xor(acc, 16, 64);
    acc += __shfl_xor(acc, 32, 64);
    if ((tid & 63) < 16) red[tid >> 6][c] = acc;
  }
  __syncthreads();

  if (tid < 16) {
    float v = bv[slice * 16 + tid];
#pragma unroll
    for (int w = 0; w < 8; ++w) v += red[w][tid];
    red[0][tid] = v;                       // stash raw v for Phase C
    vgSh[tid]   = v * gamma[slice * 16 + tid];
  }
  __syncthreads();

  // Phase C: per-batch scalar moments (one thread; 32 blocks contend lightly)
  if (tid == 0) {
    float a = 0.f, q = 0.f;
#pragma unroll
    for (int t = 0; t < 16; ++t) { float vv = red[0][t]; a += vv; q += vv * vv; }
    atomicAdd(ws + OFF_SV + bb * 16, a);
    atomicAdd(ws + OFF_SV2 + bb * 16, q);
  }

  // Phase D: split-K chunk of Az (and G/Bz on spare batches)
  {
    float acc = 0.f;
#pragma unroll
    for (int i = 0; i < 16; ++i)
      acc += vgSh[i] * Wout[(slice * 16 + i) * DD + tid];
    atomicAdd(ws + OFF_AZ + bb * DD + tid, acc);

    if (bb == 1) {
      float g = 0.f;
#pragma unroll
      for (int i = 0; i < 16; ++i)
        g += gamma[slice * 16 + i] * Wout[(slice * 16 + i) * DD + tid];
      atomicAdd(ws + OFF_G + tid, g);
    } else if (bb == 2) {
      float bz = 0.f;
#pragma unroll
      for (int i = 0; i < 16; ++i)
        bz += beta[slice * 16 + i] * Wout[(slice * 16 + i) * DD + tid];
      atomicAdd(ws + OFF_BZ + tid, bz);
    }
  }
}

// ---------------------------------------------------------------------------
// Stage 3: out[b,t,:] = inv*(Az - mu*G) + Bz, broadcast over t.
// Fill-kernel shape: 2056 blocks x 256 threads x 8 f4 stores. 514 blocks
// span exactly one batch and 2048 f4/block ≡ 0 mod 128, so all 8 stores of
// a thread share ONE value: compute the affine once, then 8 pure stores.
// ---------------------------------------------------------------------------
__global__ __launch_bounds__(256) void k_bcast(const float* __restrict__ ws,
                                               f4* __restrict__ out4) {
  const unsigned blk = blockIdx.x;
  const unsigned t   = threadIdx.x;
  const unsigned bb  = blk / 514u;                 // batch (514 blocks each)

  const float mu  = ws[OFF_SV + bb * 16] * (1.0f / (float)DD);
  const float var = ws[OFF_SV2 + bb * 16] * (1.0f / (float)DD) - mu * mu;
  const float inv = 1.0f / sqrtf(var + EPSV);

  const unsigned j4 = t & 127u;                    // column group (D/4 = 128)
  const f4 az = ((const f4*)(ws + OFF_AZ))[bb * 128u + j4];
  const f4 g  = ((const f4*)(ws + OFF_G))[j4];
  const f4 bz = ((const f4*)(ws + OFF_BZ))[j4];
  const f4 val = inv * (az - mu * g) + bz;

  f4* base = out4 + (size_t)blk * 2048 + t;
#pragma unroll
  for (int k = 0; k < 8; ++k) base[k * 256] = val;
}

// ---------------------------------------------------------------------------
extern "C" void kernel_launch(void* const* d_in, const int* in_sizes, int n_in,
                              void* d_out, int out_size, void* d_ws, size_t ws_size,
                              hipStream_t stream) {
  // setup_inputs() order:
  // 0:x 1:persistent_memory 2:Wk 3:bk 4:Wv 5:bv 6:Wq 7:bq 8:gamma 9:beta
  // 10:Wout 11:bout      (Wk/bk/Wq/bq mathematically dead — see round 1)
  const float* x     = (const float*)d_in[0];
  const float* pm    = (const float*)d_in[1];
  const float* Wv    = (const float*)d_in[4];
  const float* bv    = (const float*)d_in[5];
  const float* gamma = (const float*)d_in[8];
  const float* beta  = (const float*)d_in[9];
  const float* Wout  = (const float*)d_in[10];
  const float* bout  = (const float*)d_in[11];

  float* ws = (float*)d_ws;

  k_colsum<<<1026, 512, 0, stream>>>((const f4*)x, pm, bout, ws);

  k_mid<<<BB * 32, 512, 0, stream>>>(Wv, bv, gamma, beta, Wout, ws);

  // 4,210,688 f4 total = 2056 blocks * 256 threads * 8 stores exactly
  k_bcast<<<2056, 256, 0, stream>>>(ws, (f4*)d_out);
}